// Round 20
// baseline (78.048 us; speedup 1.0000x reference)
//
#include <hip/hip_runtime.h>
#include <hip/hip_bf16.h>

typedef __attribute__((ext_vector_type(4))) float f32x4;
typedef __attribute__((ext_vector_type(8))) short bf16x8;

#define M_TOT 30752   // 8*62*62 output pixels

__device__ __forceinline__ unsigned short f2bf(float f) {
  unsigned int u = __float_as_uint(f);
  u = u + 0x7FFF + ((u >> 16) & 1);   // round-to-nearest-even
  return (unsigned short)(u >> 16);
}

__device__ __forceinline__ void gload16(const void* g, void* l) {
  __builtin_amdgcn_global_load_lds((const __attribute__((address_space(1))) unsigned int*)g,
                                   (__attribute__((address_space(3))) unsigned int*)l,
                                   16, 0, 0);
}

// ---- fused prep: blocks 0..575 = keff+k2t (hides under cast);
//                  blocks 576..4671 = cast x->bf16 (HBM-bound).  [R16, frozen]
__global__ __launch_bounds__(256) void fused_k(const float* __restrict__ x,
                                               const float* __restrict__ P,
                                               const float* __restrict__ Q,
                                               const float* __restrict__ S,
                                               unsigned short* __restrict__ xb,
                                               unsigned short* __restrict__ K2t) {
  __shared__ float ldsK[256 * 4];
  const int bid = blockIdx.x;
  const int t = threadIdx.x;

  if (bid >= 576) {                  // ---- cast x -> bf16 ----
    int i = (bid - 576) * 256 + t;
    const f32x4* xp = (const f32x4*)x;
    f32x4 a = xp[2 * i];
    f32x4 b = xp[2 * i + 1];
    bf16x8 o;
    o[0] = (short)f2bf(a[0]); o[1] = (short)f2bf(a[1]);
    o[2] = (short)f2bf(a[2]); o[3] = (short)f2bf(a[3]);
    o[4] = (short)f2bf(b[0]); o[5] = (short)f2bf(b[1]);
    o[6] = (short)f2bf(b[2]); o[7] = (short)f2bf(b[3]);
    ((bf16x8*)xb)[i] = o;
    return;
  }

  const int kk = bid / 64;           // 0..8
  const int f0 = (bid & 63) * 4;     // 0..252
  {                                  // phase 1: Keff slice -> LDS (thread = o)
    float k0 = 0.f, k1 = 0.f, k2 = 0.f, k3 = 0.f;
    const float* qp = Q + t * 144 + kk * 16;
    const float* sp = S + (t >> 4) * 4096 + (t & 15) * 256 + f0;
#pragma unroll
    for (int bi = 0; bi < 16; ++bi) {
      float qv = qp[bi];
      const float* s4 = sp + bi * 65536;
      k0 = fmaf(qv, s4[0], k0); k1 = fmaf(qv, s4[1], k1);
      k2 = fmaf(qv, s4[2], k2); k3 = fmaf(qv, s4[3], k3);
    }
    ldsK[t * 4 + 0] = k0; ldsK[t * 4 + 1] = k1;
    ldsK[t * 4 + 2] = k2; ldsK[t * 4 + 3] = k3;
  }
  __syncthreads();
  {                                  // phase 2: contraction over o (thread = ci)
    const int ci = t;
    float acc[4] = {0.f, 0.f, 0.f, 0.f};
#pragma unroll 8
    for (int o = 0; o < 256; ++o) {
      float pv = P[o * 256 + ci];
      acc[0] = fmaf(pv, ldsK[o * 4 + 0], acc[0]);
      acc[1] = fmaf(pv, ldsK[o * 4 + 1], acc[1]);
      acc[2] = fmaf(pv, ldsK[o * 4 + 2], acc[2]);
      acc[3] = fmaf(pv, ldsK[o * 4 + 3], acc[3]);
    }
#pragma unroll
    for (int j = 0; j < 4; ++j)
      K2t[kk * 65536 + (f0 + j) * 256 + ci] = f2bf(acc[j]);
  }
}

// ---- main: implicit-GEMM conv.  M=30752, N=256, K=2304.
// 4-WAVES-PER-SIMD experiment: 512 thr = 8 waves (sk x wm x wn = 2x2x2),
// wave tile 64x64 over its K-half; BM=128, BN=128, BK=64/step. LDS 64KB
// (2 x 32KB bufs) -> 2 blocks/CU -> 16 waves/CU = 4/SIMD (was 2/SIMD in all
// prior 41us configs). launch_bounds(512,4) caps VGPR at 128 (acc = 64).
// R17 one-barrier ring; 0-conflict 64B-row swizzle; grid 488 = 8 XCD x 61.
__global__ __launch_bounds__(512, 4) void conv_gemm(const unsigned short* __restrict__ xb,
                                                    const unsigned short* __restrict__ K2t,
                                                    float* __restrict__ out) {
  __shared__ __attribute__((aligned(16))) char smem[65536];  // 2 x (A16K + B16K)

  const int tid = threadIdx.x;
  const int lane = tid & 63;
  const int wid = tid >> 6;         // 0..7
  const int sk = wid >> 2;          // k-half
  const int wm = (wid >> 1) & 1;    // m-half
  const int wn = wid & 1;           // n-half

  const int wgid = (blockIdx.x & 7) * 61 + (blockIdx.x >> 3);
  if (wgid >= 482) return;
  const int mt = wgid >> 1;         // 0..240
  const int nt = wgid & 1;
  const int m0 = mt * 128;
  const int n0 = nt * 128;

  const int rl = lane & 15;
  const int kg = lane >> 4;

  // staging: thread t (0..511) owns chunks {t, t+512} of A and of B.
  // chunk c=t: sk0, row t>>2 (0..127), stored slot t&3; c=t+512: sk1, same.
  // source data-slot = (t&3) ^ ((row>>1)&3) = (t&3) ^ ((t>>3)&3).
  const int s_src = ((tid & 3) ^ ((tid >> 3) & 3)) * 8;   // element offset
  int gA;
  {
    int m = m0 + (tid >> 2); if (m >= M_TOT) m = M_TOT - 1;
    int b = m / 3844; int rem = m - b * 3844;
    int h = rem / 62; int w = rem - h * 62;
    gA = ((b * 64 + h) * 64 + w) * 256 + s_src;
  }
  const int fB = (n0 + (tid >> 2)) * 256 + s_src;

  f32x4 zero = {0.f, 0.f, 0.f, 0.f};
  f32x4 acc[4][4];
#pragma unroll
  for (int i = 0; i < 4; ++i)
#pragma unroll
    for (int j = 0; j < 4; ++j) acc[i][j] = zero;

  // read-side: stored slot = kg ^ ((rl>>1)&3); row stride 64B, frag stride 16 rows
  const int slotr = (kg ^ ((rl >> 1) & 3)) * 16;                       // bytes
  const int aoff = sk * 8192 + (wm * 64 + rl) * 64 + slotr;            // A region
  const int boff = 16384 + sk * 8192 + (wn * 64 + rl) * 64 + slotr;    // B region

#define STAGE(t, base)                                                         \
  {                                                                            \
    int kk_ = (t) >> 2, cb_ = (t) & 3;                                         \
    int kh_ = kk_ / 3, kw_ = kk_ - kh_ * 3;                                    \
    int offA_ = kh_ * 16384 + kw_ * 256 + cb_ * 64;                            \
    int offB_ = kk_ * 65536 + cb_ * 64;                                        \
    unsigned short* bA = (unsigned short*)(base);                              \
    unsigned short* bB = (unsigned short*)((char*)(base) + 16384);             \
    gload16(xb + gA + offA_,       bA + tid * 8);                              \
    gload16(xb + gA + offA_ + 32,  bA + (tid + 512) * 8);                      \
    gload16(K2t + offB_ + fB,      bB + tid * 8);                              \
    gload16(K2t + offB_ + fB + 32, bB + (tid + 512) * 8);                      \
  }

  // prologue: stage tile 0, drain, sync
  STAGE(0, smem);
  asm volatile("s_waitcnt vmcnt(0)" ::: "memory");
  __builtin_amdgcn_sched_barrier(0);
  __builtin_amdgcn_s_barrier();
  __builtin_amdgcn_sched_barrier(0);

  for (int t = 0; t < 36; ++t) {
    char* cur = smem + (t & 1) * 32768;

    // 1) issue next tile's stage FIRST (hides under this step's compute)
    if (t < 35) STAGE(t + 1, smem + ((t + 1) & 1) * 32768);
    __builtin_amdgcn_sched_barrier(0);

    // 2) ds_read + MFMA (compiler emits counted lgkmcnt)
    bf16x8 bfr[4], af[4];
#pragma unroll
    for (int ni = 0; ni < 4; ++ni)
      bfr[ni] = *(const bf16x8*)(cur + boff + ni * 1024);
#pragma unroll
    for (int mi = 0; mi < 4; ++mi)
      af[mi] = *(const bf16x8*)(cur + aoff + mi * 1024);
    __builtin_amdgcn_s_setprio(1);
#pragma unroll
    for (int mi = 0; mi < 4; ++mi)
#pragma unroll
      for (int ni = 0; ni < 4; ++ni)
        acc[mi][ni] = __builtin_amdgcn_mfma_f32_16x16x32_bf16(
            af[mi], bfr[ni], acc[mi][ni], 0, 0, 0);
    __builtin_amdgcn_s_setprio(0);

    // 3) wait AFTER compute; single barrier covers visibility + anti-overwrite
    if (t < 35) {
      __builtin_amdgcn_sched_barrier(0);
      asm volatile("s_waitcnt vmcnt(0)" ::: "memory");
      __builtin_amdgcn_sched_barrier(0);
      __builtin_amdgcn_s_barrier();
      __builtin_amdgcn_sched_barrier(0);
    }
  }

  __syncthreads();   // main loop done; smem reused as reduction buffer

  // epilogue: sk=1 waves stage acc in LDS (4 waves x 16KB = 64KB); sk=0 adds
  // + stores. D row = m0 + wm*64 + mi*16 + kg*4 + r; col = n0 + wn*64 + ni*16 + rl.
  float* red = (float*)smem;
  if (sk == 1) {
#pragma unroll
    for (int mi = 0; mi < 4; ++mi)
#pragma unroll
      for (int ni = 0; ni < 4; ++ni)
        *(f32x4*)((char*)red + ((((wm * 2 + wn) * 4 + mi) * 4 + ni) * 64 + lane) * 16) =
            acc[mi][ni];
  }
  __syncthreads();
  if (sk == 0) {
#pragma unroll
    for (int mi = 0; mi < 4; ++mi) {
      int mb = m0 + wm * 64 + mi * 16 + kg * 4;
#pragma unroll
      for (int ni = 0; ni < 4; ++ni) {
        f32x4 o = *(f32x4*)((char*)red + ((((wm * 2 + wn) * 4 + mi) * 4 + ni) * 64 + lane) * 16);
        o += acc[mi][ni];
        int f = n0 + wn * 64 + ni * 16 + rl;
#pragma unroll
        for (int r = 0; r < 4; ++r) {
          int m = mb + r;
          if (m < M_TOT) out[m * 256 + f] = o[r];
        }
      }
    }
  }
#undef STAGE
}

extern "C" void kernel_launch(void* const* d_in, const int* in_sizes, int n_in,
                              void* d_out, int out_size, void* d_ws, size_t ws_size,
                              hipStream_t stream) {
  const float* x = (const float*)d_in[0];   // [8,64,64,256]
  const float* P = (const float*)d_in[1];   // [256,256]
  const float* Q = (const float*)d_in[2];   // [256,3,3,16]
  const float* S = (const float*)d_in[3];   // [256,16,256]
  float* out = (float*)d_out;               // [8,62,62,256]

  char* ws = (char*)d_ws;
  unsigned short* xb  = (unsigned short*)ws;               // 16,777,216 B
  unsigned short* K2t = (unsigned short*)(ws + 16777216);  //  1,179,648 B

  fused_k<<<4672, 256, 0, stream>>>(x, P, Q, S, xb, K2t);
  conv_gemm<<<488, 512, 0, stream>>>(xb, K2t, out);
}